// Round 4
// baseline (302.284 us; speedup 1.0000x reference)
//
#include <hip/hip_runtime.h>
#include <hip/hip_bf16.h>
#include <cstdint>
#include <cstddef>

typedef __bf16 bf16_t;
typedef __bf16 bf16x4 __attribute__((ext_vector_type(4)));
typedef __bf16 bf16x8 __attribute__((ext_vector_type(8)));
typedef float f32x4 __attribute__((ext_vector_type(4)));

#define GLD16(src, dst)                                                       \
    __builtin_amdgcn_global_load_lds(                                         \
        (const __attribute__((address_space(1))) void*)(src),                 \
        (__attribute__((address_space(3))) void*)(dst), 16, 0, 0)

#define BAR() __builtin_amdgcn_s_barrier()
#define WAIT_LGKM0()                                                          \
    do {                                                                      \
        asm volatile("s_waitcnt lgkmcnt(0)" ::: "memory");                    \
        __builtin_amdgcn_sched_barrier(0);                                    \
    } while (0)
#define WAIT_VM8() asm volatile("s_waitcnt vmcnt(8)" ::: "memory")
#define WAIT_VM0() asm volatile("s_waitcnt vmcnt(0)" ::: "memory")

// ---------------------------------------------------------------------------
// x fp32 -> bf16, vectorized (G13)
// ---------------------------------------------------------------------------
__global__ __launch_bounds__(256) void cvt_x_kernel(const float* __restrict__ x,
                                                    bf16_t* __restrict__ xb, int n4) {
    int idx = blockIdx.x * blockDim.x + threadIdx.x;
    int stride = gridDim.x * blockDim.x;
    const f32x4* xv = (const f32x4*)x;
    bf16x4* ov = (bf16x4*)xb;
    for (int i = idx; i < n4; i += stride) {
        f32x4 v = xv[i];
        bf16x4 o;
        o[0] = (bf16_t)v[0];
        o[1] = (bf16_t)v[1];
        o[2] = (bf16_t)v[2];
        o[3] = (bf16_t)v[3];
        ov[i] = o;
    }
}

// ---------------------------------------------------------------------------
// Build Mt[n][k] (bf16, [N][K]) from the quaternion Hamilton block structure.
// ---------------------------------------------------------------------------
__global__ __launch_bounds__(256) void pack_w_kernel(const float* __restrict__ Wa,
                                                     const float* __restrict__ Wb,
                                                     const float* __restrict__ Wc,
                                                     const float* __restrict__ Wd,
                                                     bf16_t* __restrict__ Mt) {
    __shared__ float tile[64][65];
    const int kb = blockIdx.x * 64;
    const int nb = blockIdx.y * 64;
    const int i = kb >> 10;
    const int j = nb >> 10;

    const float* W[4] = {Wa, Wb, Wc, Wd};
    const int srcIdx[4][4] = {{0, 1, 2, 3}, {1, 0, 3, 2}, {2, 3, 0, 1}, {3, 2, 1, 0}};
    const float sgn[4][4] = {{1.f, 1.f, 1.f, 1.f},
                             {-1.f, 1.f, -1.f, 1.f},
                             {-1.f, 1.f, 1.f, -1.f},
                             {-1.f, -1.f, 1.f, 1.f}};
    const float* Ws = W[srcIdx[i][j]];
    const float s = sgn[i][j];

    const int kq = kb & 1023;
    const int nq = nb & 1023;
    const int tx = threadIdx.x & 63;
    const int ty = threadIdx.x >> 6;

    for (int r = ty; r < 64; r += 4)
        tile[r][tx] = Ws[(size_t)(kq + r) * 1024 + (nq + tx)];
    __syncthreads();
    for (int r = ty; r < 64; r += 4)
        Mt[(size_t)(nb + r) * 4096 + (kb + tx)] = (bf16_t)(s * tile[tx][r]);
}

// ---------------------------------------------------------------------------
// 256x256 8-phase GEMM, C = A[M][K] * Bt[N][K]^T + bias.
// 512 threads = 8 waves (2Mx4N), each owns 128x64. BK=64, 128B per tile row.
// LDS 128 KiB: A dbuf [0,64K), B dbuf [64K,128K); half-tile = [128 rows][64 k].
// T2 swizzle: 16B-block' = block ^ (row&7); linear gload_lds dest +
// inverse-permuted global source (rule 21); read addr ((4c+l4)^(l15&7))*16.
// Deep prefetch (this round): tile t stages ALL of tile t+2 (B halves at p2,
// A halves at p3 -- legal: B-region reads complete by p1-end barrier, A-region
// reads by p2-end barrier, both enforced by the per-phase lgkmcnt(0)).
// One counted vmcnt(8) per tile: t+1 fully landed, t+2's 8 loads in flight.
// ---------------------------------------------------------------------------
__global__ __launch_bounds__(512, 2) void qgemm_kernel(const bf16_t* __restrict__ A,
                                                       const bf16_t* __restrict__ Bt,
                                                       const float* __restrict__ bias,
                                                       float* __restrict__ C) {
    constexpr int N = 4096, K = 4096;
    constexpr int NT = K / 64;
    extern __shared__ __align__(16) char lds[];

    const int tid = threadIdx.x;
    const int w = tid >> 6;
    const int lane = tid & 63;
    const int l15 = lane & 15, l4 = lane >> 4;
    const int wr = w >> 2, wc = w & 3;  // 2 x 4 wave grid

    // XCD-aware swizzle (512 = 8*64, bijective)
    const int wg = blockIdx.x;
    const int swz = (wg & 7) * 64 + (wg >> 3);
    const int brow = (swz >> 4) * 256;  // 32 tile rows
    const int bcol = (swz & 15) * 256;  // 16 tile cols

    // staging: LDS stores k-block' = kb ^ (row&7); dest linear, global source
    // k-block for lane slot (lane&7) at row (lane>>3) is the inverse perm:
    const int srow = lane >> 3;
    const int skb = (lane & 7) ^ (lane >> 3);

    auto stageA = [&](int buf, int h, int tt) {
#pragma unroll
        for (int q = 0; q < 2; ++q) {
            const bf16_t* src = A + (size_t)(brow + h * 128 + w * 16 + q * 8 + srow) * K +
                                tt * 64 + skb * 8;
            GLD16(src, lds + buf * 32768 + h * 16384 + w * 2048 + q * 1024);
        }
    };
    auto stageB = [&](int buf, int h, int tt) {
#pragma unroll
        for (int q = 0; q < 2; ++q) {
            const bf16_t* src = Bt + (size_t)(bcol + h * 128 + w * 16 + q * 8 + srow) * K +
                                tt * 64 + skb * 8;
            GLD16(src, lds + 65536 + buf * 32768 + h * 16384 + w * 2048 + q * 1024);
        }
    };

    f32x4 acc[8][4] = {};
    bf16x8 a[4][2], b0[2][2], b1[2][2];

    // swizzled read: fragment (row R, k-chunk c): 16B at R*128 + ((4c+l4)^(R&7))*16
    auto ldA = [&](int buf, int mh) {
#pragma unroll
        for (int m = 0; m < 4; ++m)
#pragma unroll
            for (int c = 0; c < 2; ++c)
                a[m][c] = *(const bf16x8*)(lds + buf * 32768 + wr * 16384 +
                                           (mh * 64 + m * 16 + l15) * 128 +
                                           ((c * 4 + l4) ^ (l15 & 7)) * 16);
    };
    auto ldB = [&](int buf, int nh, bf16x8(&b)[2][2]) {
#pragma unroll
        for (int n = 0; n < 2; ++n)
#pragma unroll
            for (int c = 0; c < 2; ++c)
                b[n][c] = *(const bf16x8*)(lds + 65536 + buf * 32768 + (wc >> 1) * 16384 +
                                           ((wc & 1) * 64 + nh * 32 + n * 16 + l15) * 128 +
                                           ((c * 4 + l4) ^ (l15 & 7)) * 16);
    };
    auto mmac = [&](int mh, int nh, bf16x8(&b)[2][2]) {
        __builtin_amdgcn_s_setprio(1);
#pragma unroll
        for (int m = 0; m < 4; ++m)
#pragma unroll
            for (int n = 0; n < 2; ++n)
#pragma unroll
                for (int c = 0; c < 2; ++c)
                    acc[mh * 4 + m][nh * 2 + n] = __builtin_amdgcn_mfma_f32_16x16x32_bf16(
                        a[m][c], b[n][c], acc[mh * 4 + m][nh * 2 + n], 0, 0, 0);
        __builtin_amdgcn_s_setprio(0);
    };

    // prologue: tile0 full (8 loads, buf0) + tile1 full (8 loads, buf1);
    // wait oldest 8 (tile0), leave tile1's 8 in flight.
    stageA(0, 0, 0);
    stageA(0, 1, 0);
    stageB(0, 0, 0);
    stageB(0, 1, 0);
    stageA(1, 0, 1);
    stageA(1, 1, 1);
    stageB(1, 0, 1);
    stageB(1, 1, 1);
    WAIT_VM8();
    BAR();

    for (int tt = 0; tt < NT; ++tt) {
        const int cur = tt & 1;
        // phase 0: quadrant (mh=0, nh=0) -- no staging
        ldA(cur, 0);
        ldB(cur, 0, b0);
        BAR();
        WAIT_LGKM0();
        mmac(0, 0, b0);
        BAR();
        // phase 1: (0,1) -- no staging
        ldB(cur, 1, b1);
        BAR();
        WAIT_LGKM0();
        mmac(0, 1, b1);
        BAR();
        // phase 2: (1,1); stage B halves for t+2 into live buffer
        // (all B-region ds_reads completed by p1-end barrier)
        ldA(cur, 1);
        if (tt + 2 < NT) {
            stageB(cur, 0, tt + 2);
            stageB(cur, 1, tt + 2);
        }
        BAR();
        WAIT_LGKM0();
        mmac(1, 1, b1);
        BAR();
        // phase 3: (1,0); stage A halves for t+2 into live buffer
        // (all A-region ds_reads completed by p2-end barrier)
        if (tt + 2 < NT) {
            stageA(cur, 0, tt + 2);
            stageA(cur, 1, tt + 2);
        }
        BAR();
        WAIT_LGKM0();
        mmac(1, 0, b0);
        // counted vmcnt: drain t+1's 8 loads, keep t+2's 8 in flight
        if (tt + 2 < NT) {
            WAIT_VM8();
        } else {
            WAIT_VM0();  // tail: drain everything
        }
        BAR();
    }

    // epilogue: C/D layout col = lane&15, row = (lane>>4)*4 + i
#pragma unroll
    for (int n = 0; n < 4; ++n) {
        const int col = bcol + wc * 64 + n * 16 + l15;
        const float bv = bias[col];
#pragma unroll
        for (int m = 0; m < 8; ++m) {
            const int row0 = brow + wr * 128 + m * 16 + l4 * 4;
            const f32x4 v = acc[m][n];
#pragma unroll
            for (int i = 0; i < 4; ++i)
                C[(size_t)(row0 + i) * N + col] = v[i] + bv;
        }
    }
}

// ---------------------------------------------------------------------------
extern "C" void kernel_launch(void* const* d_in, const int* in_sizes, int n_in,
                              void* d_out, int out_size, void* d_ws, size_t ws_size,
                              hipStream_t stream) {
    const float* x = (const float*)d_in[0];
    const float* Wa = (const float*)d_in[1];
    const float* Wb = (const float*)d_in[2];
    const float* Wc = (const float*)d_in[3];
    const float* Wd = (const float*)d_in[4];
    const float* bias = (const float*)d_in[5];
    float* out = (float*)d_out;

    const int M = 8192, N = 4096, K = 4096;

    bf16_t* xb = (bf16_t*)d_ws;       // [M][K] bf16
    bf16_t* Mt = xb + (size_t)M * K;  // [N][K] bf16

    cvt_x_kernel<<<4096, 256, 0, stream>>>(x, xb, (M * K) / 4);
    pack_w_kernel<<<dim3(64, 64), 256, 0, stream>>>(Wa, Wb, Wc, Wd, Mt);

    (void)hipFuncSetAttribute((const void*)qgemm_kernel,
                              hipFuncAttributeMaxDynamicSharedMemorySize, 131072);
    qgemm_kernel<<<dim3((M / 256) * (N / 256)), 512, 131072, stream>>>(xb, Mt, bias, out);
}

// Round 5
// 286.129 us; speedup vs baseline: 1.0565x; 1.0565x over previous
//
#include <hip/hip_runtime.h>
#include <hip/hip_bf16.h>
#include <cstdint>
#include <cstddef>

typedef __bf16 bf16_t;
typedef __bf16 bf16x4 __attribute__((ext_vector_type(4)));
typedef __bf16 bf16x8 __attribute__((ext_vector_type(8)));
typedef float f32x4 __attribute__((ext_vector_type(4)));

#define GLD16(src, dst)                                                       \
    __builtin_amdgcn_global_load_lds(                                         \
        (const __attribute__((address_space(1))) void*)(src),                 \
        (__attribute__((address_space(3))) void*)(dst), 16, 0, 0)

#define BAR() __builtin_amdgcn_s_barrier()
#define WAIT_LGKM0()                                                          \
    do {                                                                      \
        asm volatile("s_waitcnt lgkmcnt(0)" ::: "memory");                    \
        __builtin_amdgcn_sched_barrier(0);                                    \
    } while (0)
#define WAIT_VM6() asm volatile("s_waitcnt vmcnt(6)" ::: "memory")
#define WAIT_VM0() asm volatile("s_waitcnt vmcnt(0)" ::: "memory")

// ---------------------------------------------------------------------------
// x fp32 -> bf16, vectorized (G13)
// ---------------------------------------------------------------------------
__global__ __launch_bounds__(256) void cvt_x_kernel(const float* __restrict__ x,
                                                    bf16_t* __restrict__ xb, int n4) {
    int idx = blockIdx.x * blockDim.x + threadIdx.x;
    int stride = gridDim.x * blockDim.x;
    const f32x4* xv = (const f32x4*)x;
    bf16x4* ov = (bf16x4*)xb;
    for (int i = idx; i < n4; i += stride) {
        f32x4 v = xv[i];
        bf16x4 o;
        o[0] = (bf16_t)v[0];
        o[1] = (bf16_t)v[1];
        o[2] = (bf16_t)v[2];
        o[3] = (bf16_t)v[3];
        ov[i] = o;
    }
}

// ---------------------------------------------------------------------------
// Build Mt[n][k] (bf16, [N][K]) from the quaternion Hamilton block structure.
// ---------------------------------------------------------------------------
__global__ __launch_bounds__(256) void pack_w_kernel(const float* __restrict__ Wa,
                                                     const float* __restrict__ Wb,
                                                     const float* __restrict__ Wc,
                                                     const float* __restrict__ Wd,
                                                     bf16_t* __restrict__ Mt) {
    __shared__ float tile[64][65];
    const int kb = blockIdx.x * 64;
    const int nb = blockIdx.y * 64;
    const int i = kb >> 10;
    const int j = nb >> 10;

    const float* W[4] = {Wa, Wb, Wc, Wd};
    const int srcIdx[4][4] = {{0, 1, 2, 3}, {1, 0, 3, 2}, {2, 3, 0, 1}, {3, 2, 1, 0}};
    const float sgn[4][4] = {{1.f, 1.f, 1.f, 1.f},
                             {-1.f, 1.f, -1.f, 1.f},
                             {-1.f, 1.f, 1.f, -1.f},
                             {-1.f, -1.f, 1.f, 1.f}};
    const float* Ws = W[srcIdx[i][j]];
    const float s = sgn[i][j];

    const int kq = kb & 1023;
    const int nq = nb & 1023;
    const int tx = threadIdx.x & 63;
    const int ty = threadIdx.x >> 6;

    for (int r = ty; r < 64; r += 4)
        tile[r][tx] = Ws[(size_t)(kq + r) * 1024 + (nq + tx)];
    __syncthreads();
    for (int r = ty; r < 64; r += 4)
        Mt[(size_t)(nb + r) * 4096 + (kb + tx)] = (bf16_t)(s * tile[tx][r]);
}

// ---------------------------------------------------------------------------
// 256x256 8-phase GEMM, C = A[M][K] * Bt[N][K]^T + bias.
// 512 threads = 8 waves (2Mx4N), each owns 128x64. BK=64, 128B per tile row.
// LDS 128 KiB: A dbuf [0,64K), B dbuf [64K,128K); half-tile = [128 rows][64 k].
// T2 swizzle: 16B-block' = block ^ (row&7); linear gload_lds dest +
// inverse-permuted global source (rule 21); read addr ((4c+l4)^(l15&7))*16.
// Depth-3 prefetch, BALANCED (R4 lesson: exactly one 2-load stage per phase):
//   p0: A h1 of t+1 (idle buf)   p1: B h0 of t+2 (live buf)
//   p2: B h1 of t+2 (live buf)   p3: A h0 of t+2 (live buf)
// Tile-end vmcnt(6): t+2's three halves stay in flight; all of t+1 landed.
// Region-reuse legality: Bh0/Ah0 reads done by p0-end barrier, Bh1 by p1-end,
// Ah1 by p2-end; each stage issues at least one full barrier later.
// ---------------------------------------------------------------------------
__global__ __launch_bounds__(512, 2) void qgemm_kernel(const bf16_t* __restrict__ A,
                                                       const bf16_t* __restrict__ Bt,
                                                       const float* __restrict__ bias,
                                                       float* __restrict__ C) {
    constexpr int N = 4096, K = 4096;
    constexpr int NT = K / 64;
    extern __shared__ __align__(16) char lds[];

    const int tid = threadIdx.x;
    const int w = tid >> 6;
    const int lane = tid & 63;
    const int l15 = lane & 15, l4 = lane >> 4;
    const int wr = w >> 2, wc = w & 3;  // 2 x 4 wave grid

    // XCD-aware swizzle (512 = 8*64, bijective)
    const int wg = blockIdx.x;
    const int swz = (wg & 7) * 64 + (wg >> 3);
    const int brow = (swz >> 4) * 256;  // 32 tile rows
    const int bcol = (swz & 15) * 256;  // 16 tile cols

    // staging: LDS stores k-block' = kb ^ (row&7); dest linear, global source
    // k-block for lane slot (lane&7) at row (lane>>3) is the inverse perm:
    const int srow = lane >> 3;
    const int skb = (lane & 7) ^ (lane >> 3);

    auto stageA = [&](int buf, int h, int tt) {
#pragma unroll
        for (int q = 0; q < 2; ++q) {
            const bf16_t* src = A + (size_t)(brow + h * 128 + w * 16 + q * 8 + srow) * K +
                                tt * 64 + skb * 8;
            GLD16(src, lds + buf * 32768 + h * 16384 + w * 2048 + q * 1024);
        }
    };
    auto stageB = [&](int buf, int h, int tt) {
#pragma unroll
        for (int q = 0; q < 2; ++q) {
            const bf16_t* src = Bt + (size_t)(bcol + h * 128 + w * 16 + q * 8 + srow) * K +
                                tt * 64 + skb * 8;
            GLD16(src, lds + 65536 + buf * 32768 + h * 16384 + w * 2048 + q * 1024);
        }
    };

    f32x4 acc[8][4] = {};
    bf16x8 a[4][2], b0[2][2], b1[2][2];

    // swizzled read: fragment (row R, k-chunk c): 16B at R*128 + ((4c+l4)^(R&7))*16
    auto ldA = [&](int buf, int mh) {
#pragma unroll
        for (int m = 0; m < 4; ++m)
#pragma unroll
            for (int c = 0; c < 2; ++c)
                a[m][c] = *(const bf16x8*)(lds + buf * 32768 + wr * 16384 +
                                           (mh * 64 + m * 16 + l15) * 128 +
                                           ((c * 4 + l4) ^ (l15 & 7)) * 16);
    };
    auto ldB = [&](int buf, int nh, bf16x8(&b)[2][2]) {
#pragma unroll
        for (int n = 0; n < 2; ++n)
#pragma unroll
            for (int c = 0; c < 2; ++c)
                b[n][c] = *(const bf16x8*)(lds + 65536 + buf * 32768 + (wc >> 1) * 16384 +
                                           ((wc & 1) * 64 + nh * 32 + n * 16 + l15) * 128 +
                                           ((c * 4 + l4) ^ (l15 & 7)) * 16);
    };
    auto mmac = [&](int mh, int nh, bf16x8(&b)[2][2]) {
        __builtin_amdgcn_s_setprio(1);
#pragma unroll
        for (int m = 0; m < 4; ++m)
#pragma unroll
            for (int n = 0; n < 2; ++n)
#pragma unroll
                for (int c = 0; c < 2; ++c)
                    acc[mh * 4 + m][nh * 2 + n] = __builtin_amdgcn_mfma_f32_16x16x32_bf16(
                        a[m][c], b[n][c], acc[mh * 4 + m][nh * 2 + n], 0, 0, 0);
        __builtin_amdgcn_s_setprio(0);
    };

    // prologue: tile0 full (8 loads, buf0) + tile1's Bh0/Bh1/Ah0 (6 loads, buf1);
    // vmcnt(6) drains tile0, leaves tile1's 6 in flight (steady-state entry).
    stageA(0, 0, 0);
    stageA(0, 1, 0);
    stageB(0, 0, 0);
    stageB(0, 1, 0);
    stageB(1, 0, 1);
    stageB(1, 1, 1);
    stageA(1, 0, 1);
    WAIT_VM6();
    BAR();

    for (int tt = 0; tt < NT; ++tt) {
        const int cur = tt & 1;
        // phase 0: (0,0); stage A h1 of t+1 (idle buf)
        ldA(cur, 0);
        ldB(cur, 0, b0);
        if (tt + 1 < NT) stageA(cur ^ 1, 1, tt + 1);
        BAR();
        WAIT_LGKM0();
        mmac(0, 0, b0);
        BAR();
        // phase 1: (0,1); stage B h0 of t+2 (live buf; Bh0 reads done at p0)
        ldB(cur, 1, b1);
        if (tt + 2 < NT) stageB(cur, 0, tt + 2);
        BAR();
        WAIT_LGKM0();
        mmac(0, 1, b1);
        BAR();
        // phase 2: (1,1); stage B h1 of t+2 (live buf; Bh1 reads done at p1)
        ldA(cur, 1);
        if (tt + 2 < NT) stageB(cur, 1, tt + 2);
        BAR();
        WAIT_LGKM0();
        mmac(1, 1, b1);
        BAR();
        // phase 3: (1,0); stage A h0 of t+2 (live buf; Ah0 reads done at p0)
        if (tt + 2 < NT) stageA(cur, 0, tt + 2);
        BAR();
        WAIT_LGKM0();
        mmac(1, 0, b0);
        // counted vmcnt: drain through t+1's loads, keep t+2's 6 in flight
        if (tt + 2 < NT) {
            WAIT_VM6();
        } else {
            WAIT_VM0();  // tail: all outstanding loads belong to t+1 -> drain
        }
        BAR();
    }

    // epilogue: C/D layout col = lane&15, row = (lane>>4)*4 + i
#pragma unroll
    for (int n = 0; n < 4; ++n) {
        const int col = bcol + wc * 64 + n * 16 + l15;
        const float bv = bias[col];
#pragma unroll
        for (int m = 0; m < 8; ++m) {
            const int row0 = brow + wr * 128 + m * 16 + l4 * 4;
            const f32x4 v = acc[m][n];
#pragma unroll
            for (int i = 0; i < 4; ++i)
                C[(size_t)(row0 + i) * N + col] = v[i] + bv;
        }
    }
}

// ---------------------------------------------------------------------------
extern "C" void kernel_launch(void* const* d_in, const int* in_sizes, int n_in,
                              void* d_out, int out_size, void* d_ws, size_t ws_size,
                              hipStream_t stream) {
    const float* x = (const float*)d_in[0];
    const float* Wa = (const float*)d_in[1];
    const float* Wb = (const float*)d_in[2];
    const float* Wc = (const float*)d_in[3];
    const float* Wd = (const float*)d_in[4];
    const float* bias = (const float*)d_in[5];
    float* out = (float*)d_out;

    const int M = 8192, N = 4096, K = 4096;

    bf16_t* xb = (bf16_t*)d_ws;       // [M][K] bf16
    bf16_t* Mt = xb + (size_t)M * K;  // [N][K] bf16

    cvt_x_kernel<<<4096, 256, 0, stream>>>(x, xb, (M * K) / 4);
    pack_w_kernel<<<dim3(64, 64), 256, 0, stream>>>(Wa, Wb, Wc, Wd, Mt);

    (void)hipFuncSetAttribute((const void*)qgemm_kernel,
                              hipFuncAttributeMaxDynamicSharedMemorySize, 131072);
    qgemm_kernel<<<dim3((M / 256) * (N / 256)), 512, 131072, stream>>>(xb, Mt, bias, out);
}

// Round 7
// 284.569 us; speedup vs baseline: 1.0623x; 1.0055x over previous
//
#include <hip/hip_runtime.h>
#include <hip/hip_bf16.h>
#include <cstdint>
#include <cstddef>

typedef __bf16 bf16_t;
typedef __bf16 bf16x4 __attribute__((ext_vector_type(4)));
typedef __bf16 bf16x8 __attribute__((ext_vector_type(8)));
typedef float f32x4 __attribute__((ext_vector_type(4)));

#define GLD16(src, dst)                                                       \
    __builtin_amdgcn_global_load_lds(                                         \
        (const __attribute__((address_space(1))) void*)(src),                 \
        (__attribute__((address_space(3))) void*)(dst), 16, 0, 0)

#define BAR() __builtin_amdgcn_s_barrier()
#define WAIT_VM6() asm volatile("s_waitcnt vmcnt(6)" ::: "memory")
#define WAIT_VM0() asm volatile("s_waitcnt vmcnt(0)" ::: "memory")

// ---------------------------------------------------------------------------
// x fp32 -> bf16, vectorized (G13)
// ---------------------------------------------------------------------------
__global__ __launch_bounds__(256) void cvt_x_kernel(const float* __restrict__ x,
                                                    bf16_t* __restrict__ xb, int n4) {
    int idx = blockIdx.x * blockDim.x + threadIdx.x;
    int stride = gridDim.x * blockDim.x;
    const f32x4* xv = (const f32x4*)x;
    bf16x4* ov = (bf16x4*)xb;
    for (int i = idx; i < n4; i += stride) {
        f32x4 v = xv[i];
        bf16x4 o;
        o[0] = (bf16_t)v[0];
        o[1] = (bf16_t)v[1];
        o[2] = (bf16_t)v[2];
        o[3] = (bf16_t)v[3];
        ov[i] = o;
    }
}

// ---------------------------------------------------------------------------
// Build Mt[n][k] (bf16, [N][K]) from the quaternion Hamilton block structure.
// ---------------------------------------------------------------------------
__global__ __launch_bounds__(256) void pack_w_kernel(const float* __restrict__ Wa,
                                                     const float* __restrict__ Wb,
                                                     const float* __restrict__ Wc,
                                                     const float* __restrict__ Wd,
                                                     bf16_t* __restrict__ Mt) {
    __shared__ float tile[64][65];
    const int kb = blockIdx.x * 64;
    const int nb = blockIdx.y * 64;
    const int i = kb >> 10;
    const int j = nb >> 10;

    const float* W[4] = {Wa, Wb, Wc, Wd};
    const int srcIdx[4][4] = {{0, 1, 2, 3}, {1, 0, 3, 2}, {2, 3, 0, 1}, {3, 2, 1, 0}};
    const float sgn[4][4] = {{1.f, 1.f, 1.f, 1.f},
                             {-1.f, 1.f, -1.f, 1.f},
                             {-1.f, 1.f, 1.f, -1.f},
                             {-1.f, -1.f, 1.f, 1.f}};
    const float* Ws = W[srcIdx[i][j]];
    const float s = sgn[i][j];

    const int kq = kb & 1023;
    const int nq = nb & 1023;
    const int tx = threadIdx.x & 63;
    const int ty = threadIdx.x >> 6;

    for (int r = ty; r < 64; r += 4)
        tile[r][tx] = Ws[(size_t)(kq + r) * 1024 + (nq + tx)];
    __syncthreads();
    for (int r = ty; r < 64; r += 4)
        Mt[(size_t)(nb + r) * 4096 + (kb + tx)] = (bf16_t)(s * tile[tx][r]);
}

// ---------------------------------------------------------------------------
// 256x256 8-phase GEMM, C = A[M][K] * Bt[N][K]^T + bias.
// 512 threads = 8 waves (2Mx4N), each owns 128x64. BK=64, 128B per tile row.
// LDS 128 KiB: A dbuf [0,64K), B dbuf [64K,128K); half-tile = [128 rows][64 k].
// T2 swizzle: 16B-block' = block ^ (row&7); linear gload_lds dest +
// inverse-permuted global source (rule 21); read slot ((4c+l4)^(l15&7))*16.
// Depth-3 balanced prefetch (R5 schedule): one 2-load stage per phase,
// tile-end vmcnt(6) keeps t+2's three halves in flight.
// THIS ROUND: no explicit per-phase lgkmcnt(0)/sched_barrier -- the frag
// ds_reads are C++ loads the compiler tracks; it emits counted lgkmcnt
// interleaved with the MFMA cluster (m97 asm evidence), so MFMAs start as
// soon as their first fragments land instead of after a full 12-read drain.
// vmcnt asm wait stays (compiler can't see global_load_lds->LDS deps);
// "memory" clobber orders the C++ ds_reads against it; barriers fence LDS.
// ---------------------------------------------------------------------------
__global__ __launch_bounds__(512, 2) void qgemm_kernel(const bf16_t* __restrict__ A,
                                                       const bf16_t* __restrict__ Bt,
                                                       const float* __restrict__ bias,
                                                       float* __restrict__ C) {
    constexpr int N = 4096, K = 4096;
    constexpr int NT = K / 64;
    extern __shared__ __align__(16) char lds[];

    const int tid = threadIdx.x;
    const int w = tid >> 6;
    const int lane = tid & 63;
    const int l15 = lane & 15, l4 = lane >> 4;
    const int wr = w >> 2, wc = w & 3;  // 2 x 4 wave grid

    // XCD-aware swizzle (512 = 8*64, bijective)
    const int wg = blockIdx.x;
    const int swz = (wg & 7) * 64 + (wg >> 3);
    const int brow = (swz >> 4) * 256;  // 32 tile rows
    const int bcol = (swz & 15) * 256;  // 16 tile cols

    // staging: LDS stores k-block' = kb ^ (row&7); dest linear, global source
    // k-block for lane slot (lane&7) at row (lane>>3) is the inverse perm:
    const int srow = lane >> 3;
    const int skb = (lane & 7) ^ (lane >> 3);

    auto stageA = [&](int buf, int h, int tt) {
#pragma unroll
        for (int q = 0; q < 2; ++q) {
            const bf16_t* src = A + (size_t)(brow + h * 128 + w * 16 + q * 8 + srow) * K +
                                tt * 64 + skb * 8;
            GLD16(src, lds + buf * 32768 + h * 16384 + w * 2048 + q * 1024);
        }
    };
    auto stageB = [&](int buf, int h, int tt) {
#pragma unroll
        for (int q = 0; q < 2; ++q) {
            const bf16_t* src = Bt + (size_t)(bcol + h * 128 + w * 16 + q * 8 + srow) * K +
                                tt * 64 + skb * 8;
            GLD16(src, lds + 65536 + buf * 32768 + h * 16384 + w * 2048 + q * 1024);
        }
    };

    f32x4 acc[8][4] = {};
    bf16x8 a[4][2], b0[2][2], b1[2][2];

    // swizzled read: fragment (row R, k-chunk c): 16B at R*128 + ((4c+l4)^(R&7))*16
    auto ldA = [&](int buf, int mh) {
#pragma unroll
        for (int m = 0; m < 4; ++m)
#pragma unroll
            for (int c = 0; c < 2; ++c)
                a[m][c] = *(const bf16x8*)(lds + buf * 32768 + wr * 16384 +
                                           (mh * 64 + m * 16 + l15) * 128 +
                                           ((c * 4 + l4) ^ (l15 & 7)) * 16);
    };
    auto ldB = [&](int buf, int nh, bf16x8(&b)[2][2]) {
#pragma unroll
        for (int n = 0; n < 2; ++n)
#pragma unroll
            for (int c = 0; c < 2; ++c)
                b[n][c] = *(const bf16x8*)(lds + 65536 + buf * 32768 + (wc >> 1) * 16384 +
                                           ((wc & 1) * 64 + nh * 32 + n * 16 + l15) * 128 +
                                           ((c * 4 + l4) ^ (l15 & 7)) * 16);
    };
    auto mmac = [&](int mh, int nh, bf16x8(&b)[2][2]) {
        __builtin_amdgcn_s_setprio(1);
#pragma unroll
        for (int m = 0; m < 4; ++m)
#pragma unroll
            for (int n = 0; n < 2; ++n)
#pragma unroll
                for (int c = 0; c < 2; ++c)
                    acc[mh * 4 + m][nh * 2 + n] = __builtin_amdgcn_mfma_f32_16x16x32_bf16(
                        a[m][c], b[n][c], acc[mh * 4 + m][nh * 2 + n], 0, 0, 0);
        __builtin_amdgcn_s_setprio(0);
    };

    // prologue: tile0 full (8 loads, buf0) + tile1's Bh0/Bh1/Ah0 (6 loads, buf1);
    // vmcnt(6) drains tile0, leaves tile1's 6 in flight (steady-state entry).
    stageA(0, 0, 0);
    stageA(0, 1, 0);
    stageB(0, 0, 0);
    stageB(0, 1, 0);
    stageB(1, 0, 1);
    stageB(1, 1, 1);
    stageA(1, 0, 1);
    WAIT_VM6();
    BAR();

    for (int tt = 0; tt < NT; ++tt) {
        const int cur = tt & 1;
        // phase 0: (0,0); stage A h1 of t+1 (idle buf)
        ldA(cur, 0);
        ldB(cur, 0, b0);
        if (tt + 1 < NT) stageA(cur ^ 1, 1, tt + 1);
        BAR();
        mmac(0, 0, b0);
        BAR();
        // phase 1: (0,1); stage B h0 of t+2 (live buf; Bh0 reads done at p0)
        ldB(cur, 1, b1);
        if (tt + 2 < NT) stageB(cur, 0, tt + 2);
        BAR();
        mmac(0, 1, b1);
        BAR();
        // phase 2: (1,1); stage B h1 of t+2 (live buf; Bh1 reads done at p1)
        ldA(cur, 1);
        if (tt + 2 < NT) stageB(cur, 1, tt + 2);
        BAR();
        mmac(1, 1, b1);
        BAR();
        // phase 3: (1,0); stage A h0 of t+2 (live buf; Ah0 reads done at p0)
        if (tt + 2 < NT) stageA(cur, 0, tt + 2);
        BAR();
        mmac(1, 0, b0);
        // counted vmcnt: drain through t+1's loads, keep t+2's 6 in flight
        if (tt + 2 < NT) {
            WAIT_VM6();
        } else {
            WAIT_VM0();  // tail: all outstanding loads belong to t+1 -> drain
        }
        BAR();
    }

    // epilogue: C/D layout col = lane&15, row = (lane>>4)*4 + i
#pragma unroll
    for (int n = 0; n < 4; ++n) {
        const int col = bcol + wc * 64 + n * 16 + l15;
        const float bv = bias[col];
#pragma unroll
        for (int m = 0; m < 8; ++m) {
            const int row0 = brow + wr * 128 + m * 16 + l4 * 4;
            const f32x4 v = acc[m][n];
#pragma unroll
            for (int i = 0; i < 4; ++i)
                C[(size_t)(row0 + i) * N + col] = v[i] + bv;
        }
    }
}

// ---------------------------------------------------------------------------
extern "C" void kernel_launch(void* const* d_in, const int* in_sizes, int n_in,
                              void* d_out, int out_size, void* d_ws, size_t ws_size,
                              hipStream_t stream) {
    const float* x = (const float*)d_in[0];
    const float* Wa = (const float*)d_in[1];
    const float* Wb = (const float*)d_in[2];
    const float* Wc = (const float*)d_in[3];
    const float* Wd = (const float*)d_in[4];
    const float* bias = (const float*)d_in[5];
    float* out = (float*)d_out;

    const int M = 8192, N = 4096, K = 4096;

    bf16_t* xb = (bf16_t*)d_ws;       // [M][K] bf16
    bf16_t* Mt = xb + (size_t)M * K;  // [N][K] bf16

    cvt_x_kernel<<<4096, 256, 0, stream>>>(x, xb, (M * K) / 4);
    pack_w_kernel<<<dim3(64, 64), 256, 0, stream>>>(Wa, Wb, Wc, Wd, Mt);

    (void)hipFuncSetAttribute((const void*)qgemm_kernel,
                              hipFuncAttributeMaxDynamicSharedMemorySize, 131072);
    qgemm_kernel<<<dim3((M / 256) * (N / 256)), 512, 131072, stream>>>(xb, Mt, bias, out);
}